// Round 7
// baseline (47187.000 us; speedup 1.0000x reference)
//
#include <hip/hip_runtime.h>
#include <math.h>

#define T_LEN 8192

typedef float f32x4 __attribute__((ext_vector_type(4)));
typedef int   i32x8 __attribute__((ext_vector_type(8)));

#define DPP_MAX(x, ctrl) fmaxf((x), __int_as_float(__builtin_amdgcn_update_dpp(0, __float_as_int(x), (ctrl), 0xF, 0xF, true)))

__device__ __forceinline__ float fsig(float x) {
    x = fminf(30.f, fmaxf(-30.f, x));
    float e = __expf(-x);
    return __builtin_amdgcn_rcpf(1.f + e);
}
__device__ __forceinline__ float ftanh(float x) {
    x = fminf(15.f, fmaxf(-15.f, x));
    float e = __expf(-2.f * x);
    return (1.f - e) * __builtin_amdgcn_rcpf(1.f + e);
}

// ---- OCP e2m3 (fp6) encode: sign(1) exp(2,bias1) man(3); max 7.5 ----
__device__ __forceinline__ unsigned enc_e2m3(float x) {
    unsigned s = (__float_as_uint(x) >> 31) << 5;
    float a = fabsf(x);
    a = fminf(a, 7.5f);
    if (a < 0.0625f) return s;                 // rounds to zero
    int e = ((int)((__float_as_uint(a) >> 23) & 0xffu)) - 127;  // floor(log2 a)
    int eu = e < 0 ? 0 : e;
    float ulp = __int_as_float((unsigned)(eu + 124) << 23);     // 2^(eu-3)
    float q = rintf(a * __builtin_amdgcn_rcpf(ulp));
    int E, M;
    if (e < 0) {                                // a < 1: denorm / promote
        if (q >= 8.f) { E = 1; M = 0; }
        else { E = 0; M = (int)q; }
    } else {
        if (q >= 16.f) { q = 8.f; eu += 1; }
        if (eu > 2) { E = 3; M = 7; }
        else { E = eu + 1; M = (int)q - 8; }
    }
    return s | (unsigned)(E << 3) | (unsigned)M;
}

// ---------------------------------------------------------------------------
// Kernel 1: pre = relu(embed_W[docs]) @ w_ih^T + (b_ih + b_hh)   (T x 1024)
// Output columns PERMUTED: col' = 4*unit + gate
// ---------------------------------------------------------------------------
__global__ __launch_bounds__(256, 4) void gemm_pre(
    const int* __restrict__ docs,
    const float* __restrict__ embW,
    const float* __restrict__ w_ih,
    const float* __restrict__ b_ih,
    const float* __restrict__ b_hh,
    float* __restrict__ pre)
{
    __shared__ __align__(16) float As[16][68];
    __shared__ __align__(16) float Bs[16][68];
    __shared__ int rowid[64];
    const int bt = blockIdx.x;
    const int bj = blockIdx.y;
    const int tid = threadIdx.x;
    if (tid < 64) rowid[tid] = docs[bt * 64 + tid];
    __syncthreads();
    const int ti = tid & 15, tj = tid >> 4;
    const int r = tid & 63;
    const int kk4 = (tid >> 6) * 4;
    float acc[4][4];
#pragma unroll
    for (int ii = 0; ii < 4; ++ii)
#pragma unroll
        for (int jj = 0; jj < 4; ++jj) acc[ii][jj] = 0.f;

    for (int k0 = 0; k0 < 256; k0 += 16) {
        float4 av = *(const float4*)(embW + (size_t)rowid[r] * 256 + k0 + kk4);
        float4 bv = *(const float4*)(w_ih + (size_t)(bj * 64 + r) * 256 + k0 + kk4);
        As[kk4 + 0][r] = fmaxf(av.x, 0.f);
        As[kk4 + 1][r] = fmaxf(av.y, 0.f);
        As[kk4 + 2][r] = fmaxf(av.z, 0.f);
        As[kk4 + 3][r] = fmaxf(av.w, 0.f);
        Bs[kk4 + 0][r] = bv.x;
        Bs[kk4 + 1][r] = bv.y;
        Bs[kk4 + 2][r] = bv.z;
        Bs[kk4 + 3][r] = bv.w;
        __syncthreads();
#pragma unroll
        for (int kk = 0; kk < 16; ++kk) {
            float4 a = *(const float4*)&As[kk][ti * 4];
            float4 b = *(const float4*)&Bs[kk][tj * 4];
            acc[0][0] += a.x * b.x; acc[0][1] += a.x * b.y; acc[0][2] += a.x * b.z; acc[0][3] += a.x * b.w;
            acc[1][0] += a.y * b.x; acc[1][1] += a.y * b.y; acc[1][2] += a.y * b.z; acc[1][3] += a.y * b.w;
            acc[2][0] += a.z * b.x; acc[2][1] += a.z * b.y; acc[2][2] += a.z * b.z; acc[2][3] += a.z * b.w;
            acc[3][0] += a.w * b.x; acc[3][1] += a.w * b.y; acc[3][2] += a.w * b.z; acc[3][3] += a.w * b.w;
        }
        __syncthreads();
    }
#pragma unroll
    for (int ii = 0; ii < 4; ++ii) {
        int t = bt * 64 + ti * 4 + ii;
#pragma unroll
        for (int jj = 0; jj < 4; ++jj) {
            int j = bj * 64 + tj * 4 + jj;
            int jp = ((j & 255) << 2) | (j >> 8);
            pre[(size_t)t * 1024 + jp] = acc[ii][jj] + b_ih[j] + b_hh[j];
        }
    }
}

// ---------------------------------------------------------------------------
// Kernel 2: single-workgroup LSTM scan, MX-fp6 (e2m3) K=128 MFMA GEMV.
// 1 WG x 512 threads. W_hh in VGPRs as e2m3 x32 (dense 6-bit fields, 24B/lane
// window of 32 k-values). h published as 6-bit codes packed cooperatively:
// 24 writer lanes/wave build bytes via 2 shfls each -> 24B/wave block; reader
// window (kt,kg) = wave-block 4kt+kg, read directly (b128+b64), no unpack.
// Per step: hoisted pre read | bq read | 16 MFMA (cbsz=blgp=2) | ladder |
// in-reg cell update | pack+publish | ONE barrier.
// ---------------------------------------------------------------------------
__global__ __launch_bounds__(512, 2) void lstm_scan_mx6(
    const float* __restrict__ pre,    // (T, 1024), permuted cols 4u+gate
    const float* __restrict__ w_hh,   // (1024, 256), original layout
    float* __restrict__ hs)           // (T, 256) fp32
{
    const int tid = threadIdx.x;
    const int w  = tid >> 6;          // wave 0..7
    const int l  = tid & 63;
    const int rw = l & 15;            // A-row within tile / C column
    const int kg = l >> 4;            // k-group 0..3
    const float INV = 1.f / 128.f;    // 1/(32*4)

    __shared__ __align__(16) unsigned char h6pk[2][256];  // 8 blocks x 32B per parity
    __shared__ __align__(16) float ldsPre[2][1024];

    // ---- load + quantize weights to e2m3, dense 6-bit packed, 6 dwords ----
    i32x8 wA[8][2];
#pragma unroll
    for (int rt = 0; rt < 8; ++rt) {
#pragma unroll
        for (int kt = 0; kt < 2; ++kt) {
            int rowp = ((8 * w + rt) << 4) + rw;          // permuted row 4u+gate
            int orow = ((rowp & 3) << 8) + (rowp >> 2);   // original gate-major
            const float* s = w_hh + (size_t)orow * 256 + 128 * kt + 32 * kg;
            unsigned d[6] = {0, 0, 0, 0, 0, 0};
#pragma unroll
            for (int j = 0; j < 32; ++j) {
                unsigned c = enc_e2m3(s[j] * 32.f);
                int bit = 6 * j;
                d[bit >> 5] |= c << (bit & 31);
                if ((bit & 31) > 26) d[(bit >> 5) + 1] |= c >> (32 - (bit & 31));
            }
            i32x8 v;
            v[0] = (int)d[0]; v[1] = (int)d[1]; v[2] = (int)d[2];
            v[3] = (int)d[3]; v[4] = (int)d[4]; v[5] = (int)d[5];
            v[6] = 0; v[7] = 0;
            wA[rt][kt] = v;
        }
    }

    for (int i = tid; i < 512; i += 512) h6pk[0][i] = 0;  // both parities (2*256)
    {
        float2 p = *(const float2*)(pre + 2 * tid);       // row 0 -> ldsPre[0]
        *(float2*)&ldsPre[0][2 * tid] = p;
    }

    const bool isup = (rw < 8);
    const int u = 32 * w + 4 * (rw & 7) + kg;             // unit (valid rw<8; clamped)
    float c_st = 0.f;

    // writer-lane constants (24 byte-writers per wave)
    const bool iswr = (rw < 8) && (kg < 3);
    const int bby = 8 * kg + rw;                          // byte 0..23
    const int j0  = (4 * bby) / 3;
    const int rsh = 8 * bby - 6 * j0;                     // 0,2,4
    const int lj0 = 16 * (j0 & 3) + (j0 >> 2);
    const int j1  = j0 + 1;
    const int lj1 = 16 * (j1 & 3) + (j1 >> 2);

    const float* pnext = pre + 1024 + 2 * tid;            // row t+1 stream
    float* hsp = hs + u;                                  // row t stream
    __syncthreads();

    for (int t = 0; t < T_LEN; ++t) {
        const int PW = t & 1;
        const int PR = PW ^ 1;

        // hoisted: gate bias for this step (written at t-1, barrier'd)
        f32x4 p4 = *(const f32x4*)&ldsPre[PW][4 * u];

        // stage next pre row into regs
        float2 pv = *(const float2*)pnext;
        if (t + 2 < T_LEN) pnext += 1024;

        // B: packed fp6 window (kt,kg) = wave-block 4kt+kg, 24B direct
        i32x8 bq[2];
#pragma unroll
        for (int kt = 0; kt < 2; ++kt) {
            const unsigned char* bp = &h6pk[PR][(4 * kt + kg) * 32];
            uint4 lo = *(const uint4*)bp;
            uint2 hi = *(const uint2*)(bp + 16);
            i32x8 b;
            b[0] = (int)lo.x; b[1] = (int)lo.y; b[2] = (int)lo.z; b[3] = (int)lo.w;
            b[4] = (int)hi.x; b[5] = (int)hi.y; b[6] = 0; b[7] = 0;
            bq[kt] = b;
        }

        // MFMA GEMV: 8 row-tiles x 2 k-tiles, fmt fp6/fp6 (cbsz=blgp=2)
        f32x4 acc[8];
#pragma unroll
        for (int rt = 0; rt < 8; ++rt) acc[rt] = (f32x4){0.f, 0.f, 0.f, 0.f};
#pragma unroll
        for (int rt = 0; rt < 8; ++rt)
#pragma unroll
            for (int kt = 0; kt < 2; ++kt)
                acc[rt] = __builtin_amdgcn_mfma_scale_f32_16x16x128_f8f6f4(
                    wA[rt][kt], bq[kt], acc[rt],
                    2, 2,                      // cbsz: A=fp6(e2m3), blgp: B=fp6(e2m3)
                    0, 0x7f7f7f7f,             // scale A = 1.0
                    0, 0x7f7f7f7f);            // scale B = 1.0

        // cell update: col-lane rw<8 handles tile rt=rw (static ladder select)
        int code = 0;
        if (isup) {
            f32x4 av = acc[0];
            av = (rw == 1) ? acc[1] : av;
            av = (rw == 2) ? acc[2] : av;
            av = (rw == 3) ? acc[3] : av;
            av = (rw == 4) ? acc[4] : av;
            av = (rw == 5) ? acc[5] : av;
            av = (rw == 6) ? acc[6] : av;
            av = (rw == 7) ? acc[7] : av;
            float gi = fmaf(av.x, INV, p4.x);
            float gf = fmaf(av.y, INV, p4.y);
            float gg = fmaf(av.z, INV, p4.z);
            float go = fmaf(av.w, INV, p4.w);
            float si = fsig(gi);
            float sf = fsig(gf);
            float tg = ftanh(gg);
            float so = fsig(go);
            c_st = sf * c_st + si * tg;
            float h = so * ftanh(c_st);
            hsp[0] = h;
            code = (int)enc_e2m3(h * 4.f);
        }
        hsp += 256;

        // cooperative 6-bit pack: byte b = codes j0,j0+1 (whole-wave shfls)
        int c0 = __shfl(code, lj0, 64);
        int c1 = __shfl(code, lj1, 64);
        if (iswr) {
            unsigned byte = (((unsigned)c0 >> rsh) | ((unsigned)c1 << (6 - rsh))) & 0xffu;
            h6pk[PW][w * 32 + bby] = (unsigned char)byte;
        }

        // publish staged pre for step t+1
        *(float2*)&ldsPre[PR][2 * tid] = pv;

        __syncthreads();
    }
}

// ---------------------------------------------------------------------------
// Kernel 3: conv (FN=128, FL=5) over hs + per-block max over its 64 t's.
// ---------------------------------------------------------------------------
__global__ __launch_bounds__(256) void conv_pool(
    const float* __restrict__ hs,    // (T, 256)
    const float* __restrict__ cw,    // (128, 1, 5, 256)
    const float* __restrict__ cb,    // (128,)
    float* __restrict__ part)        // (128 blocks, 128 n)
{
    __shared__ __align__(16) float hst[68 * 260];
    __shared__ __align__(16) float cwS[128 * 68];
    const int blk = blockIdx.x;
    const int t0 = blk * 64;
    const int tid = threadIdx.x;
    const int i = tid & 15;
    const int g = tid >> 4;

    for (int e = tid; e < 68 * 64; e += 256) {
        int rr = e >> 6;
        int c4 = (e & 63) * 4;
        int tg = t0 + rr; if (tg > 8191) tg = 8191;
        float4 v = *(const float4*)(hs + (size_t)tg * 256 + c4);
        *(float4*)&hst[rr * 260 + c4] = v;
    }

    float acc[4][8];
#pragma unroll
    for (int tt = 0; tt < 4; ++tt)
#pragma unroll
        for (int j = 0; j < 8; ++j) acc[tt][j] = 0.f;

    for (int l = 0; l < 5; ++l) {
        for (int hc = 0; hc < 4; ++hc) {
            __syncthreads();
            {
                int n = tid >> 1;
                int hb = (tid & 1) * 32;
                const float* src = cw + (size_t)n * 1280 + l * 256 + hc * 64 + hb;
                float* dst = &cwS[n * 68 + hb];
#pragma unroll
                for (int q = 0; q < 8; ++q) {
                    float4 v = *(const float4*)(src + 4 * q);
                    *(float4*)(dst + 4 * q) = v;
                }
            }
            __syncthreads();
#pragma unroll 4
            for (int q = 0; q < 16; ++q) {
                float4 hvv[4];
#pragma unroll
                for (int tt = 0; tt < 4; ++tt)
                    hvv[tt] = *(const float4*)&hst[(i + 16 * tt + l) * 260 + hc * 64 + 4 * q];
#pragma unroll
                for (int j = 0; j < 8; ++j) {
                    float4 wv = *(const float4*)&cwS[(g + 16 * j) * 68 + 4 * q];
#pragma unroll
                    for (int tt = 0; tt < 4; ++tt) {
                        acc[tt][j] += hvv[tt].x * wv.x + hvv[tt].y * wv.y
                                    + hvv[tt].z * wv.z + hvv[tt].w * wv.w;
                    }
                }
            }
        }
    }

    float m[8];
#pragma unroll
    for (int j = 0; j < 8; ++j) {
        int n = g + 16 * j;
        float cbn = cb[n];
        float mm = -INFINITY;
#pragma unroll
        for (int tt = 0; tt < 4; ++tt) {
            int t = t0 + i + 16 * tt;
            float v = acc[tt][j] + cbn;
            if (t < 8188) mm = fmaxf(mm, v);
        }
        mm = DPP_MAX(mm, 0xB1);
        mm = DPP_MAX(mm, 0x4E);
        mm = DPP_MAX(mm, 0x141);
        mm = DPP_MAX(mm, 0x140);
        m[j] = mm;
    }
    if (i == 0) {
#pragma unroll
        for (int j = 0; j < 8; ++j)
            part[(size_t)blk * 128 + g + 16 * j] = m[j];
    }
}

// ---------------------------------------------------------------------------
// Kernel 4: final head — pool-reduce, logits, log_softmax, loss + acc.
// ---------------------------------------------------------------------------
__global__ void final_head(
    const float* __restrict__ part,      // (128, 128)
    const float* __restrict__ logits_w,  // (20, 128)
    const float* __restrict__ logits_b,  // (20,)
    const int* __restrict__ labels,
    float* __restrict__ out)             // [loss, acc]
{
    __shared__ float pooled[128];
    __shared__ float lgt[20];
    int tid = threadIdx.x;
    float mx = -INFINITY;
    for (int b = 0; b < 128; ++b) mx = fmaxf(mx, part[(size_t)b * 128 + tid]);
    pooled[tid] = mx;
    __syncthreads();
    if (tid < 20) {
        float s = logits_b[tid];
        for (int k = 0; k < 128; ++k) s += logits_w[tid * 128 + k] * pooled[k];
        lgt[tid] = s;
    }
    __syncthreads();
    if (tid == 0) {
        float m = lgt[0]; int am = 0;
        for (int c2 = 1; c2 < 20; ++c2) { if (lgt[c2] > m) { m = lgt[c2]; am = c2; } }
        float se = 0.f;
        for (int c2 = 0; c2 < 20; ++c2) se += expf(lgt[c2] - m);
        float lse = m + logf(se);
        int lbl = labels[0];
        out[0] = -(lgt[lbl] - lse);
        out[1] = (am == lbl) ? 1.f : 0.f;
    }
}

// ---------------------------------------------------------------------------
extern "C" void kernel_launch(void* const* d_in, const int* in_sizes, int n_in,
                              void* d_out, int out_size, void* d_ws, size_t ws_size,
                              hipStream_t stream) {
    (void)in_sizes; (void)n_in; (void)out_size; (void)ws_size;
    const int*   docs   = (const int*)d_in[0];
    const int*   labels = (const int*)d_in[2];
    const float* embW   = (const float*)d_in[4];
    const float* w_ih   = (const float*)d_in[5];
    const float* w_hh   = (const float*)d_in[6];
    const float* b_ih   = (const float*)d_in[7];
    const float* b_hh   = (const float*)d_in[8];
    const float* cw     = (const float*)d_in[9];
    const float* cb     = (const float*)d_in[10];
    const float* lw     = (const float*)d_in[11];
    const float* lb     = (const float*)d_in[12];
    float* out = (float*)d_out;

    char* ws = (char*)d_ws;
    float* pre  = (float*)(ws);                    // 8192*1024*4 = 33554432
    float* hs   = (float*)(ws + 33554432);         // 8192*256*4  =  8388608
    float* part = (float*)(ws + 41943040);         // 128*128*4   =    65536

    gemm_pre<<<dim3(128, 16, 1), 256, 0, stream>>>(docs, embW, w_ih, b_ih, b_hh, pre);
    lstm_scan_mx6<<<1, 512, 0, stream>>>(pre, w_hh, hs);
    conv_pool<<<128, 256, 0, stream>>>(hs, cw, cb, part);
    final_head<<<1, 128, 0, stream>>>(part, lw, lb, labels, out);
}

// Round 8
// 6155.053 us; speedup vs baseline: 7.6664x; 7.6664x over previous
//
#include <hip/hip_runtime.h>
#include <math.h>

#define T_LEN 8192

typedef float f32x4 __attribute__((ext_vector_type(4)));
typedef int   i32x8 __attribute__((ext_vector_type(8)));

#define DPP_MAX(x, ctrl) fmaxf((x), __int_as_float(__builtin_amdgcn_update_dpp(0, __float_as_int(x), (ctrl), 0xF, 0xF, true)))

__device__ __forceinline__ float fsig(float x) {
    x = fminf(30.f, fmaxf(-30.f, x));
    float e = __expf(-x);
    return __builtin_amdgcn_rcpf(1.f + e);
}
__device__ __forceinline__ float ftanh(float x) {
    x = fminf(15.f, fmaxf(-15.f, x));
    float e = __expf(-2.f * x);
    return (1.f - e) * __builtin_amdgcn_rcpf(1.f + e);
}

// ---- OCP e4m3fn encode (HW builtin when available, manual RTN fallback) ----
__device__ __forceinline__ unsigned char enc_e4m3(float x) {
#if __has_builtin(__builtin_amdgcn_cvt_pk_fp8_f32)
    int v = __builtin_amdgcn_cvt_pk_fp8_f32(x, 0.f, 0, false);
    return (unsigned char)(v & 0xff);
#else
    unsigned u = __float_as_uint(x);
    unsigned s = (u >> 24) & 0x80u;
    float a = fabsf(x);
    if (a > 448.f) a = 448.f;
    if (a < 9.765625e-4f) return (unsigned char)s;
    int e = ((int)((__float_as_uint(a) >> 23) & 0xffu)) - 127;
    int eu = e < -6 ? -6 : e;
    float ulp = exp2f((float)(eu - 3));
    float q = rintf(a / ulp);
    int mant, ee;
    if (eu == -6 && q < 8.f) { mant = (int)q; ee = 0; }
    else {
        if (q >= 16.f) { q *= 0.5f; eu += 1; }
        mant = (int)q - 8; ee = eu + 7;
        if (ee > 15 || (ee == 15 && mant > 6)) { ee = 15; mant = 6; }
    }
    return (unsigned char)(s | (unsigned)(ee << 3) | (unsigned)mant);
#endif
}
__device__ __forceinline__ unsigned pk4(float a, float b, float c, float d) {
    return (unsigned)enc_e4m3(a) | ((unsigned)enc_e4m3(b) << 8)
         | ((unsigned)enc_e4m3(c) << 16) | ((unsigned)enc_e4m3(d) << 24);
}

// ---- OCP e2m3 (fp6) encode: sign(1) exp(2,bias1) man(3); max 7.5 ----
__device__ __forceinline__ unsigned enc_e2m3(float x) {
    unsigned s = (__float_as_uint(x) >> 31) << 5;
    float a = fabsf(x);
    a = fminf(a, 7.5f);
    if (a < 0.0625f) return s;
    int e = ((int)((__float_as_uint(a) >> 23) & 0xffu)) - 127;
    int eu = e < 0 ? 0 : e;
    float ulp = __int_as_float((unsigned)(eu + 124) << 23);     // 2^(eu-3)
    float q = rintf(a * __builtin_amdgcn_rcpf(ulp));
    int E, M;
    if (e < 0) {
        if (q >= 8.f) { E = 1; M = 0; }
        else { E = 0; M = (int)q; }
    } else {
        if (q >= 16.f) { q = 8.f; eu += 1; }
        if (eu > 2) { E = 3; M = 7; }
        else { E = eu + 1; M = (int)q - 8; }
    }
    return s | (unsigned)(E << 3) | (unsigned)M;
}

// ---------------------------------------------------------------------------
// Kernel 0: one-shot pre-pass — quantize W_hh to packed fp6 (e2m3, x32).
// Item idx = ((w*8+rt)*2+kt)*64 + l; output 8 dwords (6 used, 32B stride).
// ---------------------------------------------------------------------------
__global__ __launch_bounds__(256) void pack_w6(
    const float* __restrict__ w_hh,   // (1024, 256)
    unsigned* __restrict__ w6)        // 8192 items x 8 dwords
{
    int idx = blockIdx.x * 256 + threadIdx.x;   // 0..8191
    int l  = idx & 63;
    int kt = (idx >> 6) & 1;
    int rt = (idx >> 7) & 7;
    int w  = idx >> 10;
    int rw = l & 15, kg = l >> 4;
    int rowp = ((8 * w + rt) << 4) + rw;          // permuted row 4u+gate
    int orow = ((rowp & 3) << 8) + (rowp >> 2);   // original gate-major row
    const float* s = w_hh + (size_t)orow * 256 + 128 * kt + 32 * kg;
    unsigned d[6] = {0, 0, 0, 0, 0, 0};
#pragma unroll
    for (int j = 0; j < 32; ++j) {
        unsigned c = enc_e2m3(s[j] * 32.f);
        int bit = 6 * j;
        d[bit >> 5] |= c << (bit & 31);
        if ((bit & 31) > 26) d[(bit >> 5) + 1] |= c >> (32 - (bit & 31));
    }
    unsigned* o = w6 + (size_t)idx * 8;
    o[0] = d[0]; o[1] = d[1]; o[2] = d[2];
    o[3] = d[3]; o[4] = d[4]; o[5] = d[5];
    o[6] = 0;    o[7] = 0;
}

// ---------------------------------------------------------------------------
// Kernel 1: pre = relu(embed_W[docs]) @ w_ih^T + (b_ih + b_hh)   (T x 1024)
// Output columns PERMUTED: col' = 4*unit + gate
// ---------------------------------------------------------------------------
__global__ __launch_bounds__(256, 4) void gemm_pre(
    const int* __restrict__ docs,
    const float* __restrict__ embW,
    const float* __restrict__ w_ih,
    const float* __restrict__ b_ih,
    const float* __restrict__ b_hh,
    float* __restrict__ pre)
{
    __shared__ __align__(16) float As[16][68];
    __shared__ __align__(16) float Bs[16][68];
    __shared__ int rowid[64];
    const int bt = blockIdx.x;
    const int bj = blockIdx.y;
    const int tid = threadIdx.x;
    if (tid < 64) rowid[tid] = docs[bt * 64 + tid];
    __syncthreads();
    const int ti = tid & 15, tj = tid >> 4;
    const int r = tid & 63;
    const int kk4 = (tid >> 6) * 4;
    float acc[4][4];
#pragma unroll
    for (int ii = 0; ii < 4; ++ii)
#pragma unroll
        for (int jj = 0; jj < 4; ++jj) acc[ii][jj] = 0.f;

    for (int k0 = 0; k0 < 256; k0 += 16) {
        float4 av = *(const float4*)(embW + (size_t)rowid[r] * 256 + k0 + kk4);
        float4 bv = *(const float4*)(w_ih + (size_t)(bj * 64 + r) * 256 + k0 + kk4);
        As[kk4 + 0][r] = fmaxf(av.x, 0.f);
        As[kk4 + 1][r] = fmaxf(av.y, 0.f);
        As[kk4 + 2][r] = fmaxf(av.z, 0.f);
        As[kk4 + 3][r] = fmaxf(av.w, 0.f);
        Bs[kk4 + 0][r] = bv.x;
        Bs[kk4 + 1][r] = bv.y;
        Bs[kk4 + 2][r] = bv.z;
        Bs[kk4 + 3][r] = bv.w;
        __syncthreads();
#pragma unroll
        for (int kk = 0; kk < 16; ++kk) {
            float4 a = *(const float4*)&As[kk][ti * 4];
            float4 b = *(const float4*)&Bs[kk][tj * 4];
            acc[0][0] += a.x * b.x; acc[0][1] += a.x * b.y; acc[0][2] += a.x * b.z; acc[0][3] += a.x * b.w;
            acc[1][0] += a.y * b.x; acc[1][1] += a.y * b.y; acc[1][2] += a.y * b.z; acc[1][3] += a.y * b.w;
            acc[2][0] += a.z * b.x; acc[2][1] += a.z * b.y; acc[2][2] += a.z * b.z; acc[2][3] += a.z * b.w;
            acc[3][0] += a.w * b.x; acc[3][1] += a.w * b.y; acc[3][2] += a.w * b.z; acc[3][3] += a.w * b.w;
        }
        __syncthreads();
    }
#pragma unroll
    for (int ii = 0; ii < 4; ++ii) {
        int t = bt * 64 + ti * 4 + ii;
#pragma unroll
        for (int jj = 0; jj < 4; ++jj) {
            int j = bj * 64 + tj * 4 + jj;
            int jp = ((j & 255) << 2) | (j >> 8);
            pre[(size_t)t * 1024 + jp] = acc[ii][jj] + b_ih[j] + b_hh[j];
        }
    }
}

// ---------------------------------------------------------------------------
// Kernel 2a: single-workgroup LSTM scan, MX-fp6 (e2m3) K=128 MFMA GEMV.
// Weights pre-packed by pack_w6 -> plain b128/b64 loads (no in-kernel encoder
// -> allocator keeps wA in the unified RF like the proven fp8 variant).
// ---------------------------------------------------------------------------
__global__ __launch_bounds__(512, 2) void lstm_scan_mx6(
    const float* __restrict__ pre,    // (T, 1024), permuted cols 4u+gate
    const unsigned* __restrict__ w6,  // packed fp6 weights
    float* __restrict__ hs)           // (T, 256) fp32
{
    const int tid = threadIdx.x;
    const int w  = tid >> 6;          // wave 0..7
    const int l  = tid & 63;
    const int rw = l & 15;            // A-row within tile / C column
    const int kg = l >> 4;            // k-group 0..3
    const float INV = 1.f / 128.f;    // 1/(32*4)

    __shared__ __align__(16) unsigned char h6pk[2][256];  // 8 blocks x 32B per parity
    __shared__ __align__(16) float ldsPre[2][1024];

    // ---- load packed fp6 weights: 6 dwords + 2 zero ----
    i32x8 wA[8][2];
#pragma unroll
    for (int rt = 0; rt < 8; ++rt) {
#pragma unroll
        for (int kt = 0; kt < 2; ++kt) {
            const unsigned* s = w6 + (size_t)(((w * 8 + rt) * 2 + kt) * 64 + l) * 8;
            uint4 lo = *(const uint4*)s;
            uint2 hi = *(const uint2*)(s + 4);
            i32x8 v;
            v[0] = (int)lo.x; v[1] = (int)lo.y; v[2] = (int)lo.z;
            v[3] = (int)lo.w; v[4] = (int)hi.x; v[5] = (int)hi.y;
            v[6] = 0; v[7] = 0;
            wA[rt][kt] = v;
        }
    }

    for (int i = tid; i < 512; i += 512) h6pk[0][i] = 0;  // both parities
    {
        float2 p = *(const float2*)(pre + 2 * tid);       // row 0 -> ldsPre[0]
        *(float2*)&ldsPre[0][2 * tid] = p;
    }

    const bool isup = (rw < 8);
    const int u = 32 * w + 4 * (rw & 7) + kg;
    float c_st = 0.f;

    // writer-lane constants (24 byte-writers per wave)
    const bool iswr = (rw < 8) && (kg < 3);
    const int bby = 8 * kg + rw;                          // byte 0..23
    const int j0  = (4 * bby) / 3;
    const int rsh = 8 * bby - 6 * j0;                     // 0,2,4
    const int lj0 = 16 * (j0 & 3) + (j0 >> 2);
    const int j1  = j0 + 1;
    const int lj1 = 16 * (j1 & 3) + (j1 >> 2);

    const float* pnext = pre + 1024 + 2 * tid;
    float* hsp = hs + u;
    __syncthreads();

    for (int t = 0; t < T_LEN; ++t) {
        const int PW = t & 1;
        const int PR = PW ^ 1;

        // hoisted: gate bias for this step (written at t-1, barrier'd)
        f32x4 p4 = *(const f32x4*)&ldsPre[PW][4 * u];

        // stage next pre row into regs
        float2 pv = *(const float2*)pnext;
        if (t + 2 < T_LEN) pnext += 1024;

        // B: packed fp6 window (kt,kg) = wave-block 4kt+kg, 24B direct
        i32x8 bq[2];
#pragma unroll
        for (int kt = 0; kt < 2; ++kt) {
            const unsigned char* bp = &h6pk[PR][(4 * kt + kg) * 32];
            uint4 lo = *(const uint4*)bp;
            uint2 hi = *(const uint2*)(bp + 16);
            i32x8 b;
            b[0] = (int)lo.x; b[1] = (int)lo.y; b[2] = (int)lo.z; b[3] = (int)lo.w;
            b[4] = (int)hi.x; b[5] = (int)hi.y; b[6] = 0; b[7] = 0;
            bq[kt] = b;
        }

        // MFMA GEMV: 8 row-tiles x 2 k-tiles, fmt fp6/fp6 (cbsz=blgp=2)
        f32x4 acc[8];
#pragma unroll
        for (int rt = 0; rt < 8; ++rt) acc[rt] = (f32x4){0.f, 0.f, 0.f, 0.f};
#pragma unroll
        for (int rt = 0; rt < 8; ++rt)
#pragma unroll
            for (int kt = 0; kt < 2; ++kt)
                acc[rt] = __builtin_amdgcn_mfma_scale_f32_16x16x128_f8f6f4(
                    wA[rt][kt], bq[kt], acc[rt],
                    2, 2,                      // A=fp6(e2m3), B=fp6(e2m3)
                    0, 0x7f7f7f7f,             // scale A = 1.0
                    0, 0x7f7f7f7f);            // scale B = 1.0

        // cell update: col-lane rw<8 handles tile rt=rw
        int code = 0;
        if (isup) {
            f32x4 av = acc[0];
            av = (rw == 1) ? acc[1] : av;
            av = (rw == 2) ? acc[2] : av;
            av = (rw == 3) ? acc[3] : av;
            av = (rw == 4) ? acc[4] : av;
            av = (rw == 5) ? acc[5] : av;
            av = (rw == 6) ? acc[6] : av;
            av = (rw == 7) ? acc[7] : av;
            float gi = fmaf(av.x, INV, p4.x);
            float gf = fmaf(av.y, INV, p4.y);
            float gg = fmaf(av.z, INV, p4.z);
            float go = fmaf(av.w, INV, p4.w);
            float si = fsig(gi);
            float sf = fsig(gf);
            float tg = ftanh(gg);
            float so = fsig(go);
            c_st = sf * c_st + si * tg;
            float h = so * ftanh(c_st);
            hsp[0] = h;
            code = (int)enc_e2m3(h * 4.f);
        }
        hsp += 256;

        // cooperative 6-bit pack: byte bby = codes j0,j0+1 (whole-wave shfls)
        int c0 = __shfl(code, lj0, 64);
        int c1 = __shfl(code, lj1, 64);
        if (iswr) {
            unsigned byte = (((unsigned)c0 >> rsh) | ((unsigned)c1 << (6 - rsh))) & 0xffu;
            h6pk[PW][w * 32 + bby] = (unsigned char)byte;
        }

        // publish staged pre for step t+1
        *(float2*)&ldsPre[PR][2 * tid] = pv;

        __syncthreads();
    }
}

// ---------------------------------------------------------------------------
// Kernel 2b: fallback — round-6 proven MX-fp8 scan + tail trims.
// ---------------------------------------------------------------------------
__global__ __launch_bounds__(512, 2) void lstm_scan_mx8(
    const float* __restrict__ pre,    // (T, 1024), permuted cols 4u+gate
    const float* __restrict__ w_hh,   // (1024, 256), original layout
    float* __restrict__ hs)           // (T, 256) fp32
{
    const int tid = threadIdx.x;
    const int w  = tid >> 6;
    const int l  = tid & 63;
    const int rw = l & 15;
    const int kg = l >> 4;
    const float INV = 1.f / 32768.f;

    __shared__ __align__(16) unsigned char h8[2 * 256];
    __shared__ __align__(16) float ldsPre[2][1024];

    i32x8 wA[8][2];
#pragma unroll
    for (int rt = 0; rt < 8; ++rt) {
#pragma unroll
        for (int kt = 0; kt < 2; ++kt) {
            int rowp = ((8 * w + rt) << 4) + rw;
            int orow = ((rowp & 3) << 8) + (rowp >> 2);
            const float* s = w_hh + (size_t)orow * 256 + 128 * kt + 32 * kg;
            i32x8 v;
#pragma unroll
            for (int d = 0; d < 8; ++d) {
                float4 f = *(const float4*)(s + 4 * d);
                v[d] = (int)pk4(f.x * 512.f, f.y * 512.f, f.z * 512.f, f.w * 512.f);
            }
            wA[rt][kt] = v;
        }
    }

    for (int i = tid; i < 512; i += 512) h8[i] = 0;
    {
        float2 p = *(const float2*)(pre + 2 * tid);
        *(float2*)&ldsPre[0][2 * tid] = p;
    }
    float c_st = 0.f;
    const bool isup = (rw < 8);
    const int u = 32 * w + 4 * (rw & 7) + kg;
    const float* pnext = pre + 1024 + 2 * tid;
    float* hsp = hs + u;
    __syncthreads();

    for (int t = 0; t < T_LEN; ++t) {
        const int PW = t & 1;
        const int PR = PW ^ 1;

        f32x4 p4 = *(const f32x4*)&ldsPre[PW][4 * u];   // hoisted

        float2 pv = *(const float2*)pnext;
        if (t + 2 < T_LEN) pnext += 1024;

        i32x8 bq[2];
#pragma unroll
        for (int kt = 0; kt < 2; ++kt) {
            const unsigned char* bp = &h8[PR * 256 + 128 * kt + 32 * kg];
            uint4 lo = *(const uint4*)bp;
            uint4 hi = *(const uint4*)(bp + 16);
            i32x8 b;
            b[0] = (int)lo.x; b[1] = (int)lo.y; b[2] = (int)lo.z; b[3] = (int)lo.w;
            b[4] = (int)hi.x; b[5] = (int)hi.y; b[6] = (int)hi.z; b[7] = (int)hi.w;
            bq[kt] = b;
        }

        f32x4 acc[8];
#pragma unroll
        for (int rt = 0; rt < 8; ++rt) acc[rt] = (f32x4){0.f, 0.f, 0.f, 0.f};
#pragma unroll
        for (int rt = 0; rt < 8; ++rt)
#pragma unroll
            for (int kt = 0; kt < 2; ++kt)
                acc[rt] = __builtin_amdgcn_mfma_scale_f32_16x16x128_f8f6f4(
                    wA[rt][kt], bq[kt], acc[rt],
                    0, 0,
                    0, 0x7f7f7f7f,
                    0, 0x7f7f7f7f);

        if (isup) {
            f32x4 av = acc[0];
            av = (rw == 1) ? acc[1] : av;
            av = (rw == 2) ? acc[2] : av;
            av = (rw == 3) ? acc[3] : av;
            av = (rw == 4) ? acc[4] : av;
            av = (rw == 5) ? acc[5] : av;
            av = (rw == 6) ? acc[6] : av;
            av = (rw == 7) ? acc[7] : av;
            float gi = fmaf(av.x, INV, p4.x);
            float gf = fmaf(av.y, INV, p4.y);
            float gg = fmaf(av.z, INV, p4.z);
            float go = fmaf(av.w, INV, p4.w);
            float si = fsig(gi);
            float sf = fsig(gf);
            float tg = ftanh(gg);
            float so = fsig(go);
            c_st = sf * c_st + si * tg;
            float h = so * ftanh(c_st);
            hsp[0] = h;
            h8[PW * 256 + u] = enc_e4m3(h * 64.f);
        }
        hsp += 256;

        *(float2*)&ldsPre[PR][2 * tid] = pv;

        __syncthreads();
    }
}

// ---------------------------------------------------------------------------
// Kernel 3: conv (FN=128, FL=5) over hs + per-block max over its 64 t's.
// ---------------------------------------------------------------------------
__global__ __launch_bounds__(256) void conv_pool(
    const float* __restrict__ hs,
    const float* __restrict__ cw,
    const float* __restrict__ cb,
    float* __restrict__ part)
{
    __shared__ __align__(16) float hst[68 * 260];
    __shared__ __align__(16) float cwS[128 * 68];
    const int blk = blockIdx.x;
    const int t0 = blk * 64;
    const int tid = threadIdx.x;
    const int i = tid & 15;
    const int g = tid >> 4;

    for (int e = tid; e < 68 * 64; e += 256) {
        int rr = e >> 6;
        int c4 = (e & 63) * 4;
        int tg = t0 + rr; if (tg > 8191) tg = 8191;
        float4 v = *(const float4*)(hs + (size_t)tg * 256 + c4);
        *(float4*)&hst[rr * 260 + c4] = v;
    }

    float acc[4][8];
#pragma unroll
    for (int tt = 0; tt < 4; ++tt)
#pragma unroll
        for (int j = 0; j < 8; ++j) acc[tt][j] = 0.f;

    for (int l = 0; l < 5; ++l) {
        for (int hc = 0; hc < 4; ++hc) {
            __syncthreads();
            {
                int n = tid >> 1;
                int hb = (tid & 1) * 32;
                const float* src = cw + (size_t)n * 1280 + l * 256 + hc * 64 + hb;
                float* dst = &cwS[n * 68 + hb];
#pragma unroll
                for (int q = 0; q < 8; ++q) {
                    float4 v = *(const float4*)(src + 4 * q);
                    *(float4*)(dst + 4 * q) = v;
                }
            }
            __syncthreads();
#pragma unroll 4
            for (int q = 0; q < 16; ++q) {
                float4 hvv[4];
#pragma unroll
                for (int tt = 0; tt < 4; ++tt)
                    hvv[tt] = *(const float4*)&hst[(i + 16 * tt + l) * 260 + hc * 64 + 4 * q];
#pragma unroll
                for (int j = 0; j < 8; ++j) {
                    float4 wv = *(const float4*)&cwS[(g + 16 * j) * 68 + 4 * q];
#pragma unroll
                    for (int tt = 0; tt < 4; ++tt) {
                        acc[tt][j] += hvv[tt].x * wv.x + hvv[tt].y * wv.y
                                    + hvv[tt].z * wv.z + hvv[tt].w * wv.w;
                    }
                }
            }
        }
    }

    float m[8];
#pragma unroll
    for (int j = 0; j < 8; ++j) {
        int n = g + 16 * j;
        float cbn = cb[n];
        float mm = -INFINITY;
#pragma unroll
        for (int tt = 0; tt < 4; ++tt) {
            int t = t0 + i + 16 * tt;
            float v = acc[tt][j] + cbn;
            if (t < 8188) mm = fmaxf(mm, v);
        }
        mm = DPP_MAX(mm, 0xB1);
        mm = DPP_MAX(mm, 0x4E);
        mm = DPP_MAX(mm, 0x141);
        mm = DPP_MAX(mm, 0x140);
        m[j] = mm;
    }
    if (i == 0) {
#pragma unroll
        for (int j = 0; j < 8; ++j)
            part[(size_t)blk * 128 + g + 16 * j] = m[j];
    }
}

// ---------------------------------------------------------------------------
// Kernel 4: final head — pool-reduce, logits, log_softmax, loss + acc.
// ---------------------------------------------------------------------------
__global__ void final_head(
    const float* __restrict__ part,
    const float* __restrict__ logits_w,
    const float* __restrict__ logits_b,
    const int* __restrict__ labels,
    float* __restrict__ out)
{
    __shared__ float pooled[128];
    __shared__ float lgt[20];
    int tid = threadIdx.x;
    float mx = -INFINITY;
    for (int b = 0; b < 128; ++b) mx = fmaxf(mx, part[(size_t)b * 128 + tid]);
    pooled[tid] = mx;
    __syncthreads();
    if (tid < 20) {
        float s = logits_b[tid];
        for (int k = 0; k < 128; ++k) s += logits_w[tid * 128 + k] * pooled[k];
        lgt[tid] = s;
    }
    __syncthreads();
    if (tid == 0) {
        float m = lgt[0]; int am = 0;
        for (int c2 = 1; c2 < 20; ++c2) { if (lgt[c2] > m) { m = lgt[c2]; am = c2; } }
        float se = 0.f;
        for (int c2 = 0; c2 < 20; ++c2) se += expf(lgt[c2] - m);
        float lse = m + logf(se);
        int lbl = labels[0];
        out[0] = -(lgt[lbl] - lse);
        out[1] = (am == lbl) ? 1.f : 0.f;
    }
}

// ---------------------------------------------------------------------------
extern "C" void kernel_launch(void* const* d_in, const int* in_sizes, int n_in,
                              void* d_out, int out_size, void* d_ws, size_t ws_size,
                              hipStream_t stream) {
    (void)in_sizes; (void)n_in; (void)out_size;
    const int*   docs   = (const int*)d_in[0];
    const int*   labels = (const int*)d_in[2];
    const float* embW   = (const float*)d_in[4];
    const float* w_ih   = (const float*)d_in[5];
    const float* w_hh   = (const float*)d_in[6];
    const float* b_ih   = (const float*)d_in[7];
    const float* b_hh   = (const float*)d_in[8];
    const float* cw     = (const float*)d_in[9];
    const float* cb     = (const float*)d_in[10];
    const float* lw     = (const float*)d_in[11];
    const float* lb     = (const float*)d_in[12];
    float* out = (float*)d_out;

    char* ws = (char*)d_ws;
    float*    pre  = (float*)(ws);                 // 33554432 B
    float*    hs   = (float*)(ws + 33554432);      //  8388608 B
    float*    part = (float*)(ws + 41943040);      //    65536 B
    unsigned* w6   = (unsigned*)(ws + 42008576);   //   262144 B (fp6 weights)

    // Deterministic host-side selection: use fp6 scan only if it has zero
    // scratch (no spill) and the workspace fits the packed-weight buffer.
    hipFuncAttributes a6;
    bool ok6 = (hipFuncGetAttributes(&a6, (const void*)lstm_scan_mx6) == hipSuccess)
               && (a6.localSizeBytes == 0)
               && (ws_size >= (size_t)42270720);

    gemm_pre<<<dim3(128, 16, 1), 256, 0, stream>>>(docs, embW, w_ih, b_ih, b_hh, pre);
    if (ok6) {
        pack_w6<<<32, 256, 0, stream>>>(w_hh, w6);
        lstm_scan_mx6<<<1, 512, 0, stream>>>(pre, w6, hs);
    } else {
        lstm_scan_mx8<<<1, 512, 0, stream>>>(pre, w_hh, hs);
    }
    conv_pool<<<128, 256, 0, stream>>>(hs, cw, cb, part);
    final_head<<<1, 128, 0, stream>>>(part, lw, lb, labels, out);
}